// Round 16
// baseline (226.522 us; speedup 1.0000x reference)
//
#include <hip/hip_runtime.h>
#include <math.h>

#define NN 50000
#define NE 1200000
#define FIN 128
#define FE 32
#define H 78
#define HP 80
#define ETOT (NE + NN)

#define NPB 64                                   // nodes per bucket
#define NBUCK ((NN + NPB - 1) / NPB)             // 782
#define BCAP 2560                                // max edges/bucket in LDS

#define EB 3200                                  // edges per binning block
#define NBE ((ETOT + EB - 1) / EB)               // 391 binning blocks
#define GHN (NBUCK * NBE)                        // histogram cells
#define GS_NB ((GHN + 1023) / 1024)              // scan tiles (<=512)

#define GB ((NN + 63) / 64)                      // gemm blocks (4 waves x 16 nodes)
#define FE_WAVES 18750                           // NE/64 edges per wave
#define FEB ((FE_WAVES + 3) / 4)                 // edge-head blocks

typedef __attribute__((ext_vector_type(8))) short bf16x8;
typedef __attribute__((ext_vector_type(4))) float f32x4;

__device__ __forceinline__ unsigned short f2bf(float f) {   // RNE float->bf16
  unsigned u = __float_as_uint(f);
  return (unsigned short)((u + 0x7FFFu + ((u >> 16) & 1u)) >> 16);
}
__device__ __forceinline__ float bf2f(unsigned short b) {
  return __uint_as_float((unsigned)b << 16);
}

union Frag { uint4 q; bf16x8 v; unsigned short u[8]; };

// ---------------- prep: W permutes (split bf16, frag order) + wpc ----------------
__device__ __forceinline__ void wperm_one(const float* __restrict__ W, int K, int idx,
                                          uint4* __restrict__ out) {
  int lane = idx & 63;
  int fid = idx >> 6;
  int split = fid & 1;
  int sg = fid >> 1;
  int step = sg / 5, g = sg % 5;
  int kg = lane >> 4, l15 = lane & 15;
  int col = g * 16 + l15;
  Frag f;
#pragma unroll
  for (int e = 0; e < 8; ++e) {
    int k = step * 32 + kg * 8 + e;
    float v = (k < K && col < H) ? W[(size_t)k * H + col] : 0.f;
    unsigned short h = f2bf(v);
    if (split) h = f2bf(v - bf2f(h));
    f.u[e] = h;
  }
  out[idx] = f.q;
}

__global__ void prep_all(const float* __restrict__ W1, const float* __restrict__ W2,
                         const float* __restrict__ Wm2, const float* __restrict__ bm2,
                         const float* __restrict__ Wf, const float* __restrict__ bf,
                         uint4* __restrict__ wperm1, uint4* __restrict__ wperm2,
                         float* __restrict__ wpc) {
  int b = blockIdx.x, t = threadIdx.x;
  if (b < 10) {
    wperm_one(W1, FIN, b * 256 + t, wperm1);          // 40 frags
  } else if (b < 18) {
    int idx = (b - 10) * 256 + t;
    if (idx < 30 * 64) wperm_one(W2, H, idx, wperm2); // 30 frags
  } else {
    int k = t;
    if (k < H) {
      float s = 0.f;
      for (int j = 0; j < H; ++j) s += Wm2[k * H + j] * Wf[2 * H + j];
      wpc[k] = s;
    } else if (k == H) {
      float s = 0.f;
      for (int j = 0; j < H; ++j) s += bm2[j] * Wf[2 * H + j];
      wpc[H] = s + bf[0];
    }
  }
}

// ---------------- MFMA node GEMM: split-bf16 (~fp32 accuracy) ----------------
template<int STEPS, int LDA>
__global__ __launch_bounds__(256)
void gemm_mfma(const float* __restrict__ A, const uint4* __restrict__ wperm,
               const float* __restrict__ as, const float* __restrict__ ad,
               unsigned* __restrict__ hb, float* __restrict__ asv,
               float* __restrict__ adv) {
  int tid = threadIdx.x;
  int lane = tid & 63;
  int gw = blockIdx.x * 4 + (tid >> 6);
  int n0w = gw * 16;
  if (n0w >= NN) return;
  int l15 = lane & 15, kg = lane >> 4;
  f32x4 acc[5];
#pragma unroll
  for (int g = 0; g < 5; ++g) acc[g] = (f32x4){0.f, 0.f, 0.f, 0.f};

#pragma unroll
  for (int step = 0; step < STEPS; ++step) {
    int k0 = step * 32 + kg * 8;
    bf16x8 ah, al;
    if (k0 < LDA) {
      int row = n0w + l15;
      if (row >= NN) row = NN - 1;
      const float* ar = A + (size_t)row * LDA + k0;
      float4 f0 = *reinterpret_cast<const float4*>(ar);
      float4 f1 = *reinterpret_cast<const float4*>(ar + 4);
      float fv[8] = {f0.x, f0.y, f0.z, f0.w, f1.x, f1.y, f1.z, f1.w};
#pragma unroll
      for (int e = 0; e < 8; ++e) {
        unsigned short h = f2bf(fv[e]);
        ah[e] = (short)h;
        al[e] = (short)f2bf(fv[e] - bf2f(h));
      }
    } else {
#pragma unroll
      for (int e = 0; e < 8; ++e) { ah[e] = 0; al[e] = 0; }
    }
#pragma unroll
    for (int g = 0; g < 5; ++g) {
      Frag wh, wl;
      wh.q = wperm[((size_t)(step * 5 + g) * 2 + 0) * 64 + lane];
      wl.q = wperm[((size_t)(step * 5 + g) * 2 + 1) * 64 + lane];
      acc[g] = __builtin_amdgcn_mfma_f32_16x16x32_bf16(ah, wh.v, acc[g], 0, 0, 0);
      acc[g] = __builtin_amdgcn_mfma_f32_16x16x32_bf16(al, wh.v, acc[g], 0, 0, 0);
      acc[g] = __builtin_amdgcn_mfma_f32_16x16x32_bf16(ah, wl.v, acc[g], 0, 0, 0);
    }
  }

  float asl[5], adl[5];
#pragma unroll
  for (int g = 0; g < 5; ++g) {
    int col = g * 16 + l15;
    asl[g] = (col < H) ? as[col] : 0.f;
    adl[g] = (col < H) ? ad[col] : 0.f;
  }

#pragma unroll
  for (int r = 0; r < 4; ++r) {
    int node = n0w + kg * 4 + r;
#pragma unroll
    for (int g = 0; g < 5; ++g) {
      float c = acc[g][r];
      float cn = __shfl_xor(c, 1);
      if (!(l15 & 1) && node < NN)
        hb[(size_t)node * (HP / 2) + g * 8 + (l15 >> 1)] =
            (unsigned)f2bf(c) | ((unsigned)f2bf(cn) << 16);
    }
    float sa = 0.f, sd = 0.f;
#pragma unroll
    for (int g = 0; g < 5; ++g) {
      sa = fmaf(acc[g][r], asl[g], sa);
      sd = fmaf(acc[g][r], adl[g], sd);
    }
#pragma unroll
    for (int mask = 1; mask < 16; mask <<= 1) {
      sa += __shfl_xor(sa, mask);
      sd += __shfl_xor(sd, mask);
    }
    if (l15 == 0 && node < NN) { asv[node] = sa; adv[node] = sd; }
  }
}

// ---------------- CSR build: blocked counting sort, no global atomics --------------
__global__ __launch_bounds__(256)
void bin_hist(const int* __restrict__ ei, int* __restrict__ gh) {
  __shared__ int hist[NBUCK];
  int b = blockIdx.x, t = threadIdx.x;
  for (int k = t; k < NBUCK; k += 256) hist[k] = 0;
  __syncthreads();
  int e0 = b * EB;
  int e1 = min(e0 + EB, ETOT);
  for (int i = e0 + t; i < e1; i += 256) {
    int dst = (i < NE) ? ei[NE + i] : (i - NE);
    atomicAdd(&hist[dst >> 6], 1);
  }
  __syncthreads();
  for (int k = t; k < NBUCK; k += 256) gh[(size_t)k * NBE + b] = hist[k];
}

__global__ void scan1g(const int* __restrict__ gh, int* __restrict__ gsum) {
  __shared__ int sh[256];
  int b = blockIdx.x, t = threadIdx.x;
  int i0 = b * 1024 + t * 4;
  int s = 0;
#pragma unroll
  for (int k = 0; k < 4; ++k) {
    int i = i0 + k;
    if (i < GHN) s += gh[i];
  }
  sh[t] = s;
  __syncthreads();
  for (int off = 128; off > 0; off >>= 1) {
    if (t < off) sh[t] += sh[t + off];
    __syncthreads();
  }
  if (t == 0) gsum[b] = sh[0];
}

__global__ void scan2g(const int* __restrict__ gsum, int* __restrict__ gboff) {
  __shared__ int sh[512];
  int t = threadIdx.x;
  sh[t] = (t < GS_NB) ? gsum[t] : 0;
  __syncthreads();
  for (int off = 1; off < 512; off <<= 1) {
    int v = (t >= off) ? sh[t - off] : 0;
    __syncthreads();
    sh[t] += v;
    __syncthreads();
  }
  if (t < GS_NB) gboff[t] = (t == 0) ? 0 : sh[t - 1];
}

__global__ void scan3g(const int* __restrict__ gh, const int* __restrict__ gboff,
                       int* __restrict__ goff) {
  __shared__ int sh[256];
  int b = blockIdx.x, t = threadIdx.x;
  int i0 = b * 1024 + t * 4;
  int v[4];
  int s = 0;
#pragma unroll
  for (int k = 0; k < 4; ++k) {
    int i = i0 + k;
    v[k] = (i < GHN) ? gh[i] : 0;
    s += v[k];
  }
  sh[t] = s;
  __syncthreads();
  for (int off = 1; off < 256; off <<= 1) {
    int u = (t >= off) ? sh[t - off] : 0;
    __syncthreads();
    sh[t] += u;
    __syncthreads();
  }
  int run = gboff[b] + ((t == 0) ? 0 : sh[t - 1]);
#pragma unroll
  for (int k = 0; k < 4; ++k) {
    int i = i0 + k;
    if (i < GHN) { goff[i] = run; run += v[k]; }
  }
}

// phase 3: rank via LDS cursors; tmp packed u32 = (dst&63)<<17 | src
__global__ __launch_bounds__(256)
void bin_place(const int* __restrict__ ei, const int* __restrict__ goff,
               unsigned* __restrict__ tmp) {
  __shared__ int cursor[NBUCK];
  int b = blockIdx.x, t = threadIdx.x;
  for (int k = t; k < NBUCK; k += 256) cursor[k] = goff[(size_t)k * NBE + b];
  __syncthreads();
  int e0 = b * EB;
  int e1 = min(e0 + EB, ETOT);
  for (int i = e0 + t; i < e1; i += 256) {
    int src, dst;
    if (i < NE) { src = ei[i]; dst = ei[NE + i]; }
    else { src = dst = i - NE; }
    int pos = atomicAdd(&cursor[dst >> 6], 1);
    tmp[pos] = ((unsigned)(dst & 63) << 17) | (unsigned)src;
  }
}

__global__ __launch_bounds__(256)
void bucket_build(const unsigned* __restrict__ tmp, const int* __restrict__ goff,
                  int* __restrict__ rowptr, int* __restrict__ srcs) {
  __shared__ int hist[NPB];
  __shared__ int offs[NPB];
  __shared__ int curs[NPB];
  __shared__ int srcs_l[BCAP];
  int b = blockIdx.x, t = threadIdx.x;
  int base = goff[(size_t)b * NBE];
  int next = (b + 1 < NBUCK) ? goff[(size_t)(b + 1) * NBE] : ETOT;
  int cnt = next - base;
  int n0 = b * NPB;
  if (t < NPB) hist[t] = 0;
  __syncthreads();
  for (int p = t; p < cnt; p += 256) {
    atomicAdd(&hist[tmp[base + p] >> 17], 1);
  }
  __syncthreads();
  if (t == 0) {
    int run = 0;
    for (int j = 0; j < NPB; ++j) { offs[j] = run; run += hist[j]; }
  }
  __syncthreads();
  if (t < NPB) {
    curs[t] = offs[t];
    int n = n0 + t;
    if (n < NN) rowptr[n] = base + offs[t];
  }
  if (b == NBUCK - 1 && t == 0) rowptr[NN] = ETOT;
  __syncthreads();
  for (int p = t; p < cnt; p += 256) {
    unsigned e = tmp[base + p];
    int dstoff = e >> 17;
    int src = (int)(e & 0x1FFFFu);
    int lp = atomicAdd(&curs[dstoff], 1);
    if (lp < BCAP) srcs_l[lp] = src;
    else srcs[base + lp] = src;       // overflow fallback (statistically never)
  }
  __syncthreads();
  int m = cnt < BCAP ? cnt : BCAP;
  for (int p = t; p < m; p += 256) srcs[base + p] = srcs_l[p];
}

// ---------------- FUSED softmax + aggregation; 6 edges/iter, uint4 loads ----------
template<int RELU, int FINAL>
__global__ __launch_bounds__(256)
void gat_fused(const int* __restrict__ rowptr, const int* __restrict__ srcs,
               const float* __restrict__ asv, const float* __restrict__ adv,
               const unsigned* __restrict__ hb, const float* __restrict__ bias,
               const float* __restrict__ Wf, float* __restrict__ outp,
               float* __restrict__ uu, float* __restrict__ vv) {
  int n = (blockIdx.x * 256 + threadIdx.x) >> 6;   // wave id = node
  int lane = threadIdx.x & 63;
  if (n >= NN) return;
  int r0 = rowptr[n], r1 = rowptr[n + 1];
  int deg = r1 - r0;
  float advn = adv[n];

  // ---- phase A (deg <= 64 hot path) ----
  int s0 = 0;
  float e0 = -INFINITY;
  if (lane < deg) {
    s0 = srcs[r0 + lane];
    float e = asv[s0] + advn;
    e0 = e > 0.f ? e : 0.2f * e;
  }
  float m = e0;
#pragma unroll
  for (int off = 1; off < 64; off <<= 1) m = fmaxf(m, __shfl_xor(m, off));
  float ssum = (lane < deg) ? __expf(e0 - m) : 0.f;
#pragma unroll
  for (int off = 1; off < 64; off <<= 1) ssum += __shfl_xor(ssum, off);
  for (int c = r0 + 64; c < r1; c += 64) {      // deg>64: statistically never
    int p = c + lane;
    float e = -INFINITY;
    if (p < r1) {
      float t = asv[srcs[p]] + advn;
      e = t > 0.f ? t : 0.2f * t;
    }
    float cm = e;
#pragma unroll
    for (int off = 1; off < 64; off <<= 1) cm = fmaxf(cm, __shfl_xor(cm, off));
    float c2 = (p < r1) ? __expf(e - cm) : 0.f;
#pragma unroll
    for (int off = 1; off < 64; off <<= 1) c2 += __shfl_xor(c2, off);
    float mn = fmaxf(m, cm);
    ssum = ssum * __expf(m - mn) + c2 * __expf(cm - mn);
    m = mn;
  }
  float inv = 1.f / (ssum + 1e-16f);
  float alpha0 = (lane < deg) ? __expf(e0 - m) * inv : 0.f;

  // ---- phase B: 6 edges / iteration; 10-lane groups load uint4 (16B) ----
  int g6 = lane / 10;                  // 0..5 active; lanes 60-63 idle
  int lp = lane - g6 * 10;             // uint4 slot 0..9 (cols lp*8..lp*8+7)
  float4 aL = {0.f, 0.f, 0.f, 0.f}, aH = {0.f, 0.f, 0.f, 0.f};
  int nch = deg < 64 ? deg : 64;
  for (int base = 0; base < nch; base += 6) {
    int p = base + g6;
    bool act = (g6 < 6) && (p < nch);
    int idx = p < 63 ? p : 63;
    float al = __shfl(alpha0, idx);
    int s = __shfl(s0, idx);
    if (act) {
      uint4 q = *(reinterpret_cast<const uint4*>(hb + (size_t)s * (HP / 2)) + lp);
      aL.x = fmaf(al, bf2f((unsigned short)(q.x & 0xffff)), aL.x);
      aL.y = fmaf(al, bf2f((unsigned short)(q.x >> 16)), aL.y);
      aL.z = fmaf(al, bf2f((unsigned short)(q.y & 0xffff)), aL.z);
      aL.w = fmaf(al, bf2f((unsigned short)(q.y >> 16)), aL.w);
      aH.x = fmaf(al, bf2f((unsigned short)(q.z & 0xffff)), aH.x);
      aH.y = fmaf(al, bf2f((unsigned short)(q.z >> 16)), aH.y);
      aH.z = fmaf(al, bf2f((unsigned short)(q.w & 0xffff)), aH.z);
      aH.w = fmaf(al, bf2f((unsigned short)(q.w >> 16)), aH.w);
    }
  }
  for (int c = r0 + 64; c < r1; c += 64) {      // overflow chunks (never)
    int p = c + lane;
    float al = 0.f;
    int s = 0;
    if (p < r1) {
      s = srcs[p];
      float t = asv[s] + advn;
      t = t > 0.f ? t : 0.2f * t;
      al = __expf(t - m) * inv;
    }
    int cnt = min(r1 - c, 64);
    for (int base = 0; base < cnt; base += 6) {
      int p2 = base + g6;
      bool act = (g6 < 6) && (p2 < cnt);
      int idx = p2 < 63 ? p2 : 63;
      float alq = __shfl(al, idx);
      int sq = __shfl(s, idx);
      if (act) {
        uint4 q = *(reinterpret_cast<const uint4*>(hb + (size_t)sq * (HP / 2)) + lp);
        aL.x = fmaf(alq, bf2f((unsigned short)(q.x & 0xffff)), aL.x);
        aL.y = fmaf(alq, bf2f((unsigned short)(q.x >> 16)), aL.y);
        aL.z = fmaf(alq, bf2f((unsigned short)(q.y & 0xffff)), aL.z);
        aL.w = fmaf(alq, bf2f((unsigned short)(q.y >> 16)), aL.w);
        aH.x = fmaf(alq, bf2f((unsigned short)(q.z & 0xffff)), aH.x);
        aH.y = fmaf(alq, bf2f((unsigned short)(q.z >> 16)), aH.y);
        aH.z = fmaf(alq, bf2f((unsigned short)(q.w & 0xffff)), aH.z);
        aH.w = fmaf(alq, bf2f((unsigned short)(q.w >> 16)), aH.w);
      }
    }
  }

  // ---- reduce across the 6 groups (gather-shfl; no cascade) ----
  float o[8];
  float* av = reinterpret_cast<float*>(&aL);
#pragma unroll
  for (int j = 0; j < 4; ++j) {
    float v = av[j];
    o[j] = v + __shfl(v, lane + 10) + __shfl(v, lane + 20) + __shfl(v, lane + 30)
             + __shfl(v, lane + 40) + __shfl(v, lane + 50);
  }
  float* ah = reinterpret_cast<float*>(&aH);
#pragma unroll
  for (int j = 0; j < 4; ++j) {
    float v = ah[j];
    o[4 + j] = v + __shfl(v, lane + 10) + __shfl(v, lane + 20) + __shfl(v, lane + 30)
                 + __shfl(v, lane + 40) + __shfl(v, lane + 50);
  }

  if (FINAL) {
    float su = 0.f, sv = 0.f;
    if (lane < 10) {
      int c0 = lane * 8;
#pragma unroll
      for (int j = 0; j < 8; ++j) {
        int col = c0 + j;
        float oj = o[j] + ((col < H) ? bias[col] : 0.f);
        float wu = (col < H) ? Wf[col] : 0.f;
        float wv = (col < H) ? Wf[H + col] : 0.f;
        su = fmaf(oj, wu, su);
        sv = fmaf(oj, wv, sv);
      }
    }
#pragma unroll
    for (int off = 1; off < 64; off <<= 1) {
      su += __shfl_xor(su, off);
      sv += __shfl_xor(sv, off);
    }
    if (lane == 0) { uu[n] = su; vv[n] = sv; }
  } else {
    if (lane < 10) {
      int c0 = lane * 8;
      float4 w0, w1;
      float* pw = reinterpret_cast<float*>(&w0);
#pragma unroll
      for (int j = 0; j < 4; ++j) {
        int col = c0 + j;
        float oj = o[j] + ((col < H) ? bias[col] : 0.f);
        if (RELU) oj = fmaxf(oj, 0.f);
        pw[j] = (col < H) ? oj : 0.f;
      }
      float* pw1 = reinterpret_cast<float*>(&w1);
#pragma unroll
      for (int j = 0; j < 4; ++j) {
        int col = c0 + 4 + j;
        float oj = o[4 + j] + ((col < H) ? bias[col] : 0.f);
        if (RELU) oj = fmaxf(oj, 0.f);
        pw1[j] = (col < H) ? oj : 0.f;
      }
      float* orow = outp + (size_t)n * HP + c0;
      *reinterpret_cast<float4*>(orow) = w0;
      *reinterpret_cast<float4*>(orow + 4) = w1;
    }
  }
}

// ---------------- edge head via MFMA: ea[E x 32] @ Wm1[32 x 78] -------------
__global__ __launch_bounds__(256)
void final_edge_mfma(const int* __restrict__ ei, const float* __restrict__ ea,
                     const float* __restrict__ Wm1, const float* __restrict__ bm1,
                     const float* __restrict__ wpc, const float* __restrict__ u,
                     const float* __restrict__ v, float* __restrict__ out) {
  int lane = threadIdx.x & 63;
  long gw = (long)blockIdx.x * 4 + (threadIdx.x >> 6);
  if (gw >= FE_WAVES) return;
  int l15 = lane & 15;
  int kg = lane >> 4;                    // k-group 0..3
  bf16x8 bfrag[5];
  float bm1c[5], wpcc[5];
#pragma unroll
  for (int g = 0; g < 5; ++g) {
    int col = g * 16 + l15;
    bool valid = col < H;
    bm1c[g] = valid ? bm1[col] : 0.f;
    wpcc[g] = valid ? wpc[col] : 0.f;
#pragma unroll
    for (int e = 0; e < 8; ++e) {
      int kk = kg * 8 + e;
      bfrag[g][e] = valid ? (short)f2bf(Wm1[kk * H + col]) : (short)0;
    }
  }
  float basec = wpc[H];
  int e0 = (int)(gw * 64);
#pragma unroll
  for (int t = 0; t < 4; ++t) {
    int ebase = e0 + t * 16;
    const float* ar = ea + (size_t)(ebase + l15) * FE + kg * 8;
    float4 f0 = *reinterpret_cast<const float4*>(ar);
    float4 f1 = *reinterpret_cast<const float4*>(ar + 4);
    bf16x8 afrag;
    afrag[0] = (short)f2bf(f0.x); afrag[1] = (short)f2bf(f0.y);
    afrag[2] = (short)f2bf(f0.z); afrag[3] = (short)f2bf(f0.w);
    afrag[4] = (short)f2bf(f1.x); afrag[5] = (short)f2bf(f1.y);
    afrag[6] = (short)f2bf(f1.z); afrag[7] = (short)f2bf(f1.w);
    float es0 = 0.f, es1 = 0.f, es2 = 0.f, es3 = 0.f;
#pragma unroll
    for (int g = 0; g < 5; ++g) {
      f32x4 c = {0.f, 0.f, 0.f, 0.f};
      c = __builtin_amdgcn_mfma_f32_16x16x32_bf16(afrag, bfrag[g], c, 0, 0, 0);
      es0 = fmaf(fmaxf(c[0] + bm1c[g], 0.f), wpcc[g], es0);
      es1 = fmaf(fmaxf(c[1] + bm1c[g], 0.f), wpcc[g], es1);
      es2 = fmaf(fmaxf(c[2] + bm1c[g], 0.f), wpcc[g], es2);
      es3 = fmaf(fmaxf(c[3] + bm1c[g], 0.f), wpcc[g], es3);
    }
#pragma unroll
    for (int m = 1; m < 16; m <<= 1) {
      es0 += __shfl_xor(es0, m);
      es1 += __shfl_xor(es1, m);
      es2 += __shfl_xor(es2, m);
      es3 += __shfl_xor(es3, m);
    }
    if (l15 < 4) {
      float es = (l15 == 0) ? es0 : (l15 == 1) ? es1 : (l15 == 2) ? es2 : es3;
      int e = ebase + kg * 4 + l15;
      int s = ei[e], d = ei[NE + e];
      out[e] = es + u[s] + v[d] + basec;
    }
  }
}

extern "C" void kernel_launch(void* const* d_in, const int* in_sizes, int n_in,
                              void* d_out, int out_size, void* d_ws, size_t ws_size,
                              hipStream_t stream) {
  const float* x   = (const float*)d_in[0];
  const int*   ei  = (const int*)d_in[1];
  const float* ea  = (const float*)d_in[2];
  const float* W1  = (const float*)d_in[3];
  const float* as1 = (const float*)d_in[4];
  const float* ad1 = (const float*)d_in[5];
  const float* b1  = (const float*)d_in[6];
  const float* W2  = (const float*)d_in[7];
  const float* as2 = (const float*)d_in[8];
  const float* ad2 = (const float*)d_in[9];
  const float* b2  = (const float*)d_in[10];
  const float* Wm1 = (const float*)d_in[11];
  const float* bm1 = (const float*)d_in[12];
  const float* Wm2 = (const float*)d_in[13];
  const float* bm2 = (const float*)d_in[14];
  const float* Wf  = (const float*)d_in[15];
  const float* bf  = (const float*)d_in[16];
  float* out = (float*)d_out;

  float* w = (float*)d_ws;
  float* bufB = w; w += (size_t)NN * HP;   // layer1 agg out = layer2 gemm input
  unsigned* hb = (unsigned*)w; w += (size_t)NN * (HP / 2);  // bf16 h (packed)
  uint4* wperm1 = (uint4*)w; w += 4 * 40 * 64;
  uint4* wperm2 = (uint4*)w; w += 4 * 30 * 64;
  float* asv  = w; w += NN;
  float* adv  = w; w += NN;
  float* uu   = w; w += NN;
  float* vv   = w; w += NN;
  float* wpc  = w; w += HP;
  unsigned* tmp = (unsigned*)w; w += ETOT;
  int* rowptr = (int*)w; w += NN + 1;
  int* srcs   = (int*)w; w += ETOT;
  int* gh     = (int*)w; w += GHN;
  int* goff   = (int*)w; w += GHN;
  int* gsum   = (int*)w; w += GS_NB;
  int* gboff  = (int*)w; w += GS_NB;

  const int B = 256;
  dim3 gW((NN * 64 + B - 1) / B);          // gat_fused: wave per node

  // ---- prep (W permutes + wpc) ----
  prep_all<<<19, B, 0, stream>>>(W1, W2, Wm2, bm2, Wf, bf, wperm1, wperm2, wpc);

  // ---- CSR build: blocked counting sort (no global atomics) ----
  bin_hist<<<NBE, B, 0, stream>>>(ei, gh);
  scan1g<<<GS_NB, B, 0, stream>>>(gh, gsum);
  scan2g<<<1, 512, 0, stream>>>(gsum, gboff);
  scan3g<<<GS_NB, B, 0, stream>>>(gh, gboff, goff);
  bin_place<<<NBE, B, 0, stream>>>(ei, goff, tmp);
  bucket_build<<<NBUCK, B, 0, stream>>>(tmp, goff, rowptr, srcs);

  // ---- layer 1 ----
  gemm_mfma<4, FIN><<<GB, B, 0, stream>>>(x, wperm1, as1, ad1, hb, asv, adv);
  gat_fused<1, 0><<<gW, B, 0, stream>>>(rowptr, srcs, asv, adv, hb, b1, Wf,
                                        bufB, uu, vv);

  // ---- layer 2 (u,v fused into epilogue) ----
  gemm_mfma<3, HP><<<GB, B, 0, stream>>>(bufB, wperm2, as2, ad2, hb, asv, adv);
  gat_fused<0, 1><<<gW, B, 0, stream>>>(rowptr, srcs, asv, adv, hb, b2, Wf,
                                        nullptr, uu, vv);

  // ---- edge head ----
  final_edge_mfma<<<FEB, B, 0, stream>>>(ei, ea, Wm1, bm1, wpc, uu, vv, out);
}

// Round 17
// 217.586 us; speedup vs baseline: 1.0411x; 1.0411x over previous
//
#include <hip/hip_runtime.h>
#include <math.h>

#define NN 50000
#define NE 1200000
#define FIN 128
#define FE 32
#define H 78
#define HP 80
#define ETOT (NE + NN)

#define NPB 64                                   // nodes per bucket
#define NBUCK ((NN + NPB - 1) / NPB)             // 782
#define BCAP 2560                                // max edges/bucket in LDS

#define EB 3200                                  // edges per binning block
#define NBE ((ETOT + EB - 1) / EB)               // 391 binning blocks
#define GHN (NBUCK * NBE)                        // histogram cells
#define GS_NB ((GHN + 1023) / 1024)              // scan tiles (<=512)

#define GB ((NN + 63) / 64)                      // gemm blocks (4 waves x 16 nodes)
#define FE_WAVES 18750                           // NE/64 edges per wave
#define FEB ((FE_WAVES + 3) / 4)                 // edge-head blocks

typedef __attribute__((ext_vector_type(8))) short bf16x8;
typedef __attribute__((ext_vector_type(4))) float f32x4;

__device__ __forceinline__ unsigned short f2bf(float f) {   // RNE float->bf16
  unsigned u = __float_as_uint(f);
  return (unsigned short)((u + 0x7FFFu + ((u >> 16) & 1u)) >> 16);
}
__device__ __forceinline__ float bf2f(unsigned short b) {
  return __uint_as_float((unsigned)b << 16);
}

union Frag { uint4 q; bf16x8 v; unsigned short u[8]; };

// ---------------- prep: W permutes (split bf16, frag order) + wpc ----------------
__device__ __forceinline__ void wperm_one(const float* __restrict__ W, int K, int idx,
                                          uint4* __restrict__ out) {
  int lane = idx & 63;
  int fid = idx >> 6;
  int split = fid & 1;
  int sg = fid >> 1;
  int step = sg / 5, g = sg % 5;
  int kg = lane >> 4, l15 = lane & 15;
  int col = g * 16 + l15;
  Frag f;
#pragma unroll
  for (int e = 0; e < 8; ++e) {
    int k = step * 32 + kg * 8 + e;
    float v = (k < K && col < H) ? W[(size_t)k * H + col] : 0.f;
    unsigned short h = f2bf(v);
    if (split) h = f2bf(v - bf2f(h));
    f.u[e] = h;
  }
  out[idx] = f.q;
}

__global__ void prep_all(const float* __restrict__ W1, const float* __restrict__ W2,
                         const float* __restrict__ Wm2, const float* __restrict__ bm2,
                         const float* __restrict__ Wf, const float* __restrict__ bf,
                         uint4* __restrict__ wperm1, uint4* __restrict__ wperm2,
                         float* __restrict__ wpc) {
  int b = blockIdx.x, t = threadIdx.x;
  if (b < 10) {
    wperm_one(W1, FIN, b * 256 + t, wperm1);          // 40 frags
  } else if (b < 18) {
    int idx = (b - 10) * 256 + t;
    if (idx < 30 * 64) wperm_one(W2, H, idx, wperm2); // 30 frags
  } else {
    int k = t;
    if (k < H) {
      float s = 0.f;
      for (int j = 0; j < H; ++j) s += Wm2[k * H + j] * Wf[2 * H + j];
      wpc[k] = s;
    } else if (k == H) {
      float s = 0.f;
      for (int j = 0; j < H; ++j) s += bm2[j] * Wf[2 * H + j];
      wpc[H] = s + bf[0];
    }
  }
}

// ---------------- MFMA node GEMM: split-bf16 (~fp32 accuracy) ----------------
template<int STEPS, int LDA>
__global__ __launch_bounds__(256)
void gemm_mfma(const float* __restrict__ A, const uint4* __restrict__ wperm,
               const float* __restrict__ as, const float* __restrict__ ad,
               unsigned* __restrict__ hb, float* __restrict__ asv,
               float* __restrict__ adv) {
  int tid = threadIdx.x;
  int lane = tid & 63;
  int gw = blockIdx.x * 4 + (tid >> 6);
  int n0w = gw * 16;
  if (n0w >= NN) return;
  int l15 = lane & 15, kg = lane >> 4;
  f32x4 acc[5];
#pragma unroll
  for (int g = 0; g < 5; ++g) acc[g] = (f32x4){0.f, 0.f, 0.f, 0.f};

#pragma unroll
  for (int step = 0; step < STEPS; ++step) {
    int k0 = step * 32 + kg * 8;
    bf16x8 ah, al;
    if (k0 < LDA) {
      int row = n0w + l15;
      if (row >= NN) row = NN - 1;
      const float* ar = A + (size_t)row * LDA + k0;
      float4 f0 = *reinterpret_cast<const float4*>(ar);
      float4 f1 = *reinterpret_cast<const float4*>(ar + 4);
      float fv[8] = {f0.x, f0.y, f0.z, f0.w, f1.x, f1.y, f1.z, f1.w};
#pragma unroll
      for (int e = 0; e < 8; ++e) {
        unsigned short h = f2bf(fv[e]);
        ah[e] = (short)h;
        al[e] = (short)f2bf(fv[e] - bf2f(h));
      }
    } else {
#pragma unroll
      for (int e = 0; e < 8; ++e) { ah[e] = 0; al[e] = 0; }
    }
#pragma unroll
    for (int g = 0; g < 5; ++g) {
      Frag wh, wl;
      wh.q = wperm[((size_t)(step * 5 + g) * 2 + 0) * 64 + lane];
      wl.q = wperm[((size_t)(step * 5 + g) * 2 + 1) * 64 + lane];
      acc[g] = __builtin_amdgcn_mfma_f32_16x16x32_bf16(ah, wh.v, acc[g], 0, 0, 0);
      acc[g] = __builtin_amdgcn_mfma_f32_16x16x32_bf16(al, wh.v, acc[g], 0, 0, 0);
      acc[g] = __builtin_amdgcn_mfma_f32_16x16x32_bf16(ah, wl.v, acc[g], 0, 0, 0);
    }
  }

  float asl[5], adl[5];
#pragma unroll
  for (int g = 0; g < 5; ++g) {
    int col = g * 16 + l15;
    asl[g] = (col < H) ? as[col] : 0.f;
    adl[g] = (col < H) ? ad[col] : 0.f;
  }

#pragma unroll
  for (int r = 0; r < 4; ++r) {
    int node = n0w + kg * 4 + r;
#pragma unroll
    for (int g = 0; g < 5; ++g) {
      float c = acc[g][r];
      float cn = __shfl_xor(c, 1);
      if (!(l15 & 1) && node < NN)
        hb[(size_t)node * (HP / 2) + g * 8 + (l15 >> 1)] =
            (unsigned)f2bf(c) | ((unsigned)f2bf(cn) << 16);
    }
    float sa = 0.f, sd = 0.f;
#pragma unroll
    for (int g = 0; g < 5; ++g) {
      sa = fmaf(acc[g][r], asl[g], sa);
      sd = fmaf(acc[g][r], adl[g], sd);
    }
#pragma unroll
    for (int mask = 1; mask < 16; mask <<= 1) {
      sa += __shfl_xor(sa, mask);
      sd += __shfl_xor(sd, mask);
    }
    if (l15 == 0 && node < NN) { asv[node] = sa; adv[node] = sd; }
  }
}

// ---------------- CSR build: blocked counting sort, no global atomics --------------
__global__ __launch_bounds__(256)
void bin_hist(const int* __restrict__ ei, int* __restrict__ gh) {
  __shared__ int hist[NBUCK];
  int b = blockIdx.x, t = threadIdx.x;
  for (int k = t; k < NBUCK; k += 256) hist[k] = 0;
  __syncthreads();
  int e0 = b * EB;
  int e1 = min(e0 + EB, ETOT);
  for (int i = e0 + t; i < e1; i += 256) {
    int dst = (i < NE) ? ei[NE + i] : (i - NE);
    atomicAdd(&hist[dst >> 6], 1);
  }
  __syncthreads();
  for (int k = t; k < NBUCK; k += 256) gh[(size_t)k * NBE + b] = hist[k];
}

__global__ void scan1g(const int* __restrict__ gh, int* __restrict__ gsum) {
  __shared__ int sh[256];
  int b = blockIdx.x, t = threadIdx.x;
  int i0 = b * 1024 + t * 4;
  int s = 0;
#pragma unroll
  for (int k = 0; k < 4; ++k) {
    int i = i0 + k;
    if (i < GHN) s += gh[i];
  }
  sh[t] = s;
  __syncthreads();
  for (int off = 128; off > 0; off >>= 1) {
    if (t < off) sh[t] += sh[t + off];
    __syncthreads();
  }
  if (t == 0) gsum[b] = sh[0];
}

__global__ void scan2g(const int* __restrict__ gsum, int* __restrict__ gboff) {
  __shared__ int sh[512];
  int t = threadIdx.x;
  sh[t] = (t < GS_NB) ? gsum[t] : 0;
  __syncthreads();
  for (int off = 1; off < 512; off <<= 1) {
    int v = (t >= off) ? sh[t - off] : 0;
    __syncthreads();
    sh[t] += v;
    __syncthreads();
  }
  if (t < GS_NB) gboff[t] = (t == 0) ? 0 : sh[t - 1];
}

__global__ void scan3g(const int* __restrict__ gh, const int* __restrict__ gboff,
                       int* __restrict__ goff) {
  __shared__ int sh[256];
  int b = blockIdx.x, t = threadIdx.x;
  int i0 = b * 1024 + t * 4;
  int v[4];
  int s = 0;
#pragma unroll
  for (int k = 0; k < 4; ++k) {
    int i = i0 + k;
    v[k] = (i < GHN) ? gh[i] : 0;
    s += v[k];
  }
  sh[t] = s;
  __syncthreads();
  for (int off = 1; off < 256; off <<= 1) {
    int u = (t >= off) ? sh[t - off] : 0;
    __syncthreads();
    sh[t] += u;
    __syncthreads();
  }
  int run = gboff[b] + ((t == 0) ? 0 : sh[t - 1]);
#pragma unroll
  for (int k = 0; k < 4; ++k) {
    int i = i0 + k;
    if (i < GHN) { goff[i] = run; run += v[k]; }
  }
}

__global__ __launch_bounds__(256)
void bin_place(const int* __restrict__ ei, const int* __restrict__ goff,
               unsigned long long* __restrict__ tmp) {
  __shared__ int cursor[NBUCK];
  int b = blockIdx.x, t = threadIdx.x;
  for (int k = t; k < NBUCK; k += 256) cursor[k] = goff[(size_t)k * NBE + b];
  __syncthreads();
  int e0 = b * EB;
  int e1 = min(e0 + EB, ETOT);
  for (int i = e0 + t; i < e1; i += 256) {
    int src, dst;
    if (i < NE) { src = ei[i]; dst = ei[NE + i]; }
    else { src = dst = i - NE; }
    int pos = atomicAdd(&cursor[dst >> 6], 1);
    tmp[pos] = ((unsigned long long)(unsigned)dst << 32) | (unsigned)src;
  }
}

__global__ __launch_bounds__(256)
void bucket_build(const unsigned long long* __restrict__ tmp,
                  const int* __restrict__ goff,
                  int* __restrict__ rowptr, int* __restrict__ srcs) {
  __shared__ int hist[NPB];
  __shared__ int offs[NPB];
  __shared__ int curs[NPB];
  __shared__ int srcs_l[BCAP];
  int b = blockIdx.x, t = threadIdx.x;
  int base = goff[(size_t)b * NBE];
  int next = (b + 1 < NBUCK) ? goff[(size_t)(b + 1) * NBE] : ETOT;
  int cnt = next - base;
  int n0 = b * NPB;
  if (t < NPB) hist[t] = 0;
  __syncthreads();
  for (int p = t; p < cnt; p += 256) {
    int dst = (int)(tmp[base + p] >> 32);
    atomicAdd(&hist[dst - n0], 1);
  }
  __syncthreads();
  if (t == 0) {
    int run = 0;
    for (int j = 0; j < NPB; ++j) { offs[j] = run; run += hist[j]; }
  }
  __syncthreads();
  if (t < NPB) {
    curs[t] = offs[t];
    int n = n0 + t;
    if (n < NN) rowptr[n] = base + offs[t];
  }
  if (b == NBUCK - 1 && t == 0) rowptr[NN] = ETOT;
  __syncthreads();
  for (int p = t; p < cnt; p += 256) {
    unsigned long long e = tmp[base + p];
    int dst = (int)(e >> 32);
    int src = (int)(e & 0xffffffffULL);
    int lp = atomicAdd(&curs[dst - n0], 1);
    if (lp < BCAP) srcs_l[lp] = src;
    else srcs[base + lp] = src;       // overflow fallback (statistically never)
  }
  __syncthreads();
  int m = cnt < BCAP ? cnt : BCAP;
  for (int p = t; p < m; p += 256) srcs[base + p] = srcs_l[p];
}

// ---------------- FUSED softmax + aggregation; 3 edges/iter, uint2 loads ----------
template<int RELU, int FINAL>
__global__ __launch_bounds__(256)
void gat_fused(const int* __restrict__ rowptr, const int* __restrict__ srcs,
               const float* __restrict__ asv, const float* __restrict__ adv,
               const unsigned* __restrict__ hb, const float* __restrict__ bias,
               const float* __restrict__ Wf, float* __restrict__ outp,
               float* __restrict__ uu, float* __restrict__ vv) {
  int n = (blockIdx.x * 256 + threadIdx.x) >> 6;   // wave id = node
  int lane = threadIdx.x & 63;
  if (n >= NN) return;
  int r0 = rowptr[n], r1 = rowptr[n + 1];
  int deg = r1 - r0;
  float advn = adv[n];

  // ---- phase A (deg <= 64 hot path) ----
  int s0 = 0;
  float e0 = -INFINITY;
  if (lane < deg) {
    s0 = srcs[r0 + lane];
    float e = asv[s0] + advn;
    e0 = e > 0.f ? e : 0.2f * e;
  }
  float m = e0;
#pragma unroll
  for (int off = 1; off < 64; off <<= 1) m = fmaxf(m, __shfl_xor(m, off));
  float ssum = (lane < deg) ? __expf(e0 - m) : 0.f;
#pragma unroll
  for (int off = 1; off < 64; off <<= 1) ssum += __shfl_xor(ssum, off);
  for (int c = r0 + 64; c < r1; c += 64) {      // deg>64: statistically never
    int p = c + lane;
    float e = -INFINITY;
    if (p < r1) {
      float t = asv[srcs[p]] + advn;
      e = t > 0.f ? t : 0.2f * t;
    }
    float cm = e;
#pragma unroll
    for (int off = 1; off < 64; off <<= 1) cm = fmaxf(cm, __shfl_xor(cm, off));
    float c2 = (p < r1) ? __expf(e - cm) : 0.f;
#pragma unroll
    for (int off = 1; off < 64; off <<= 1) c2 += __shfl_xor(c2, off);
    float mn = fmaxf(m, cm);
    ssum = ssum * __expf(m - mn) + c2 * __expf(cm - mn);
    m = mn;
  }
  float inv = 1.f / (ssum + 1e-16f);
  float alpha0 = (lane < deg) ? __expf(e0 - m) * inv : 0.f;

  // ---- phase B: 3 edges / iteration; 20-lane groups load uint2 (8B) ----
  int g3 = lane / 20;                  // 0..2 active, 3 = idle (lanes 60-63)
  int lp = lane - g3 * 20;             // float4 column group 0..19
  float4 acc = {0.f, 0.f, 0.f, 0.f};
  int nch = deg < 64 ? deg : 64;
  for (int base = 0; base < nch; base += 3) {
    int p = base + g3;
    bool act = (g3 < 3) && (p < nch);
    int idx = p < 63 ? p : 63;
    float al = __shfl(alpha0, idx);
    int s = __shfl(s0, idx);
    if (act) {
      uint2 w01 = *reinterpret_cast<const uint2*>(hb + (size_t)s * (HP / 2) + lp * 2);
      acc.x = fmaf(al, bf2f((unsigned short)(w01.x & 0xffff)), acc.x);
      acc.y = fmaf(al, bf2f((unsigned short)(w01.x >> 16)), acc.y);
      acc.z = fmaf(al, bf2f((unsigned short)(w01.y & 0xffff)), acc.z);
      acc.w = fmaf(al, bf2f((unsigned short)(w01.y >> 16)), acc.w);
    }
  }
  for (int c = r0 + 64; c < r1; c += 64) {      // overflow chunks (never)
    int p = c + lane;
    float al = 0.f;
    int s = 0;
    if (p < r1) {
      s = srcs[p];
      float t = asv[s] + advn;
      t = t > 0.f ? t : 0.2f * t;
      al = __expf(t - m) * inv;
    }
    int cnt = min(r1 - c, 64);
    for (int base = 0; base < cnt; base += 3) {
      int p2 = base + g3;
      bool act = (g3 < 3) && (p2 < cnt);
      int idx = p2 < 63 ? p2 : 63;
      float alq = __shfl(al, idx);
      int sq = __shfl(s, idx);
      if (act) {
        uint2 w01 = *reinterpret_cast<const uint2*>(hb + (size_t)sq * (HP / 2) + lp * 2);
        acc.x = fmaf(alq, bf2f((unsigned short)(w01.x & 0xffff)), acc.x);
        acc.y = fmaf(alq, bf2f((unsigned short)(w01.x >> 16)), acc.y);
        acc.z = fmaf(alq, bf2f((unsigned short)(w01.y & 0xffff)), acc.z);
        acc.w = fmaf(alq, bf2f((unsigned short)(w01.y >> 16)), acc.w);
      }
    }
  }

  // ---- cross-group reduce ----
  float4 a1, a2;
  a1.x = __shfl(acc.x, lane + 20); a1.y = __shfl(acc.y, lane + 20);
  a1.z = __shfl(acc.z, lane + 20); a1.w = __shfl(acc.w, lane + 20);
  a2.x = __shfl(acc.x, lane + 40); a2.y = __shfl(acc.y, lane + 40);
  a2.z = __shfl(acc.z, lane + 40); a2.w = __shfl(acc.w, lane + 40);

  if (FINAL) {
    // fused final_node: u = row . Wf[0:H], v = row . Wf[H:2H]; b2 folded here
    float su = 0.f, sv = 0.f;
    if (lane < 20) {
      int c0 = lane * 4;
      float o0 = acc.x + a1.x + a2.x + ((c0 + 0 < H) ? bias[c0 + 0] : 0.f);
      float o1 = acc.y + a1.y + a2.y + ((c0 + 1 < H) ? bias[c0 + 1] : 0.f);
      float o2 = acc.z + a1.z + a2.z + ((c0 + 2 < H) ? bias[c0 + 2] : 0.f);
      float o3 = acc.w + a1.w + a2.w + ((c0 + 3 < H) ? bias[c0 + 3] : 0.f);
      float wu0 = (c0 + 0 < H) ? Wf[c0 + 0] : 0.f;
      float wu1 = (c0 + 1 < H) ? Wf[c0 + 1] : 0.f;
      float wu2 = (c0 + 2 < H) ? Wf[c0 + 2] : 0.f;
      float wu3 = (c0 + 3 < H) ? Wf[c0 + 3] : 0.f;
      float wv0 = (c0 + 0 < H) ? Wf[H + c0 + 0] : 0.f;
      float wv1 = (c0 + 1 < H) ? Wf[H + c0 + 1] : 0.f;
      float wv2 = (c0 + 2 < H) ? Wf[H + c0 + 2] : 0.f;
      float wv3 = (c0 + 3 < H) ? Wf[H + c0 + 3] : 0.f;
      su = o0 * wu0 + o1 * wu1 + o2 * wu2 + o3 * wu3;
      sv = o0 * wv0 + o1 * wv1 + o2 * wv2 + o3 * wv3;
    }
#pragma unroll
    for (int off = 1; off < 64; off <<= 1) {
      su += __shfl_xor(su, off);
      sv += __shfl_xor(sv, off);
    }
    if (lane == 0) { uu[n] = su; vv[n] = sv; }
  } else {
    if (lane < 20) {
      int c0 = lane * 4;
      float4 o;
      o.x = acc.x + a1.x + a2.x + ((c0 + 0 < H) ? bias[c0 + 0] : 0.f);
      o.y = acc.y + a1.y + a2.y + ((c0 + 1 < H) ? bias[c0 + 1] : 0.f);
      o.z = acc.z + a1.z + a2.z + ((c0 + 2 < H) ? bias[c0 + 2] : 0.f);
      o.w = acc.w + a1.w + a2.w + ((c0 + 3 < H) ? bias[c0 + 3] : 0.f);
      if (RELU) {
        o.x = fmaxf(o.x, 0.f); o.y = fmaxf(o.y, 0.f);
        o.z = fmaxf(o.z, 0.f); o.w = fmaxf(o.w, 0.f);
      }
      *reinterpret_cast<float4*>(outp + (size_t)n * HP + c0) = o;
    }
  }
}

// ---------------- edge head via MFMA: ea[E x 32] @ Wm1[32 x 78] -------------
__global__ __launch_bounds__(256)
void final_edge_mfma(const int* __restrict__ ei, const float* __restrict__ ea,
                     const float* __restrict__ Wm1, const float* __restrict__ bm1,
                     const float* __restrict__ wpc, const float* __restrict__ u,
                     const float* __restrict__ v, float* __restrict__ out) {
  int lane = threadIdx.x & 63;
  long gw = (long)blockIdx.x * 4 + (threadIdx.x >> 6);
  if (gw >= FE_WAVES) return;
  int l15 = lane & 15;
  int kg = lane >> 4;                    // k-group 0..3
  bf16x8 bfrag[5];
  float bm1c[5], wpcc[5];
#pragma unroll
  for (int g = 0; g < 5; ++g) {
    int col = g * 16 + l15;
    bool valid = col < H;
    bm1c[g] = valid ? bm1[col] : 0.f;
    wpcc[g] = valid ? wpc[col] : 0.f;
#pragma unroll
    for (int e = 0; e < 8; ++e) {
      int kk = kg * 8 + e;
      bfrag[g][e] = valid ? (short)f2bf(Wm1[kk * H + col]) : (short)0;
    }
  }
  float basec = wpc[H];
  int e0 = (int)(gw * 64);
#pragma unroll
  for (int t = 0; t < 4; ++t) {
    int ebase = e0 + t * 16;
    const float* ar = ea + (size_t)(ebase + l15) * FE + kg * 8;
    float4 f0 = *reinterpret_cast<const float4*>(ar);
    float4 f1 = *reinterpret_cast<const float4*>(ar + 4);
    bf16x8 afrag;
    afrag[0] = (short)f2bf(f0.x); afrag[1] = (short)f2bf(f0.y);
    afrag[2] = (short)f2bf(f0.z); afrag[3] = (short)f2bf(f0.w);
    afrag[4] = (short)f2bf(f1.x); afrag[5] = (short)f2bf(f1.y);
    afrag[6] = (short)f2bf(f1.z); afrag[7] = (short)f2bf(f1.w);
    float es0 = 0.f, es1 = 0.f, es2 = 0.f, es3 = 0.f;
#pragma unroll
    for (int g = 0; g < 5; ++g) {
      f32x4 c = {0.f, 0.f, 0.f, 0.f};
      c = __builtin_amdgcn_mfma_f32_16x16x32_bf16(afrag, bfrag[g], c, 0, 0, 0);
      es0 = fmaf(fmaxf(c[0] + bm1c[g], 0.f), wpcc[g], es0);
      es1 = fmaf(fmaxf(c[1] + bm1c[g], 0.f), wpcc[g], es1);
      es2 = fmaf(fmaxf(c[2] + bm1c[g], 0.f), wpcc[g], es2);
      es3 = fmaf(fmaxf(c[3] + bm1c[g], 0.f), wpcc[g], es3);
    }
#pragma unroll
    for (int m = 1; m < 16; m <<= 1) {
      es0 += __shfl_xor(es0, m);
      es1 += __shfl_xor(es1, m);
      es2 += __shfl_xor(es2, m);
      es3 += __shfl_xor(es3, m);
    }
    if (l15 < 4) {
      float es = (l15 == 0) ? es0 : (l15 == 1) ? es1 : (l15 == 2) ? es2 : es3;
      int e = ebase + kg * 4 + l15;
      int s = ei[e], d = ei[NE + e];
      out[e] = es + u[s] + v[d] + basec;
    }
  }
}

extern "C" void kernel_launch(void* const* d_in, const int* in_sizes, int n_in,
                              void* d_out, int out_size, void* d_ws, size_t ws_size,
                              hipStream_t stream) {
  const float* x   = (const float*)d_in[0];
  const int*   ei  = (const int*)d_in[1];
  const float* ea  = (const float*)d_in[2];
  const float* W1  = (const float*)d_in[3];
  const float* as1 = (const float*)d_in[4];
  const float* ad1 = (const float*)d_in[5];
  const float* b1  = (const float*)d_in[6];
  const float* W2  = (const float*)d_in[7];
  const float* as2 = (const float*)d_in[8];
  const float* ad2 = (const float*)d_in[9];
  const float* b2  = (const float*)d_in[10];
  const float* Wm1 = (const float*)d_in[11];
  const float* bm1 = (const float*)d_in[12];
  const float* Wm2 = (const float*)d_in[13];
  const float* bm2 = (const float*)d_in[14];
  const float* Wf  = (const float*)d_in[15];
  const float* bf  = (const float*)d_in[16];
  float* out = (float*)d_out;

  float* w = (float*)d_ws;
  float* bufB = w; w += (size_t)NN * HP;   // layer1 agg out = layer2 gemm input
  unsigned* hb = (unsigned*)w; w += (size_t)NN * (HP / 2);  // bf16 h (packed)
  uint4* wperm1 = (uint4*)w; w += 4 * 40 * 64;
  uint4* wperm2 = (uint4*)w; w += 4 * 30 * 64;
  float* asv  = w; w += NN;
  float* adv  = w; w += NN;
  float* uu   = w; w += NN;
  float* vv   = w; w += NN;
  float* wpc  = w; w += HP;
  unsigned long long* tmp = (unsigned long long*)w; w += 2 * (size_t)ETOT;
  int* rowptr = (int*)w; w += NN + 1;
  int* srcs   = (int*)w; w += ETOT;
  int* gh     = (int*)w; w += GHN;
  int* goff   = (int*)w; w += GHN;
  int* gsum   = (int*)w; w += GS_NB;
  int* gboff  = (int*)w; w += GS_NB;

  const int B = 256;
  dim3 gW((NN * 64 + B - 1) / B);          // gat_fused: wave per node

  // ---- prep (W permutes + wpc) ----
  prep_all<<<19, B, 0, stream>>>(W1, W2, Wm2, bm2, Wf, bf, wperm1, wperm2, wpc);

  // ---- CSR build: blocked counting sort (no global atomics) ----
  bin_hist<<<NBE, B, 0, stream>>>(ei, gh);
  scan1g<<<GS_NB, B, 0, stream>>>(gh, gsum);
  scan2g<<<1, 512, 0, stream>>>(gsum, gboff);
  scan3g<<<GS_NB, B, 0, stream>>>(gh, gboff, goff);
  bin_place<<<NBE, B, 0, stream>>>(ei, goff, tmp);
  bucket_build<<<NBUCK, B, 0, stream>>>(tmp, goff, rowptr, srcs);

  // ---- layer 1 ----
  gemm_mfma<4, FIN><<<GB, B, 0, stream>>>(x, wperm1, as1, ad1, hb, asv, adv);
  gat_fused<1, 0><<<gW, B, 0, stream>>>(rowptr, srcs, asv, adv, hb, b1, Wf,
                                        bufB, uu, vv);

  // ---- layer 2 (u,v fused into epilogue) ----
  gemm_mfma<3, HP><<<GB, B, 0, stream>>>(bufB, wperm2, as2, ad2, hb, asv, adv);
  gat_fused<0, 1><<<gW, B, 0, stream>>>(rowptr, srcs, asv, adv, hb, b2, Wf,
                                        nullptr, uu, vv);

  // ---- edge head ----
  final_edge_mfma<<<FEB, B, 0, stream>>>(ei, ea, Wm1, bm1, wpc, uu, vv, out);
}